// Round 7
// baseline (474.077 us; speedup 1.0000x reference)
//
#include <hip/hip_runtime.h>
#include <hip/hip_cooperative_groups.h>
#include <math.h>

namespace cg = cooperative_groups;

#define NP 196
#define PI_F 3.14159265358979323846f
#define GRID 512  // 2 blocks/CU: well under cooperative capacity at VGPR<=128
                  // (R6 post-mortem: GRID=1024 sat at exact capacity -> launch rejected)

// order-preserving float<->uint encoding (monotone: min of keys == key of min)
__device__ __forceinline__ unsigned fkey(float f) {
  unsigned u = __float_as_uint(f);
  return u ^ ((unsigned)((int)u >> 31) | 0x80000000u);
}
__device__ __forceinline__ float funkey(unsigned k) {
  unsigned u = (k & 0x80000000u) ? (k ^ 0x80000000u) : ~k;
  return __uint_as_float(u);
}

// ---------------------------------------------------------------------------
// One cooperative kernel, phases separated by grid.sync():
//  P0: U (block 0), W2 (grid-stride), per-block patch min/max partials
//  P1: blocks 0..195 finalize per-patch min / angle-scale
//  P2: grid-stride circuits, TWO samples per thread sharing U-row LDS reads
//  P3: grid-stride wave-per-image classifier + log_softmax
// No early returns; every thread reaches every grid.sync().
// ---------------------------------------------------------------------------
struct Samp {
  float st[16];
  const float* px;
};

__device__ __forceinline__ void load_state(const float* __restrict__ x,
                                           const float* __restrict__ smn,
                                           const float* __restrict__ ssc,
                                           int g, float st[16]) {
  const int b = g / NP;
  const int p = g - b * NP;
  const int i = p / 14, j = p - i * 14;
  const float* px = x + (size_t)b * 784 + (2 * i) * 28 + 2 * j;
  const float2 r0 = *(const float2*)px;
  const float2 r1 = *(const float2*)(px + 28);
  const float mnv = smn[p], sc = ssc[p];
  float cc[4], ss[4];
  __sincosf((r0.x - mnv) * sc, &ss[0], &cc[0]);
  __sincosf((r0.y - mnv) * sc, &ss[1], &cc[1]);
  __sincosf((r1.x - mnv) * sc, &ss[2], &cc[2]);
  __sincosf((r1.y - mnv) * sc, &ss[3], &cc[3]);
  const float A[4] = {cc[0] * cc[1], cc[0] * ss[1], ss[0] * cc[1], ss[0] * ss[1]};
  const float Bq[4] = {cc[2] * cc[3], cc[2] * ss[3], ss[2] * cc[3], ss[2] * ss[3]};
#pragma unroll
  for (int idx = 0; idx < 16; ++idx) st[idx] = A[idx >> 2] * Bq[idx & 3];
}

__global__ void __launch_bounds__(256, 4) fused_kernel(
    const float* __restrict__ x, const float* __restrict__ params,
    const float* __restrict__ res_w, const float* __restrict__ cls_w,
    const float* __restrict__ cls_b, float* __restrict__ out,
    float* __restrict__ Ug, float* __restrict__ W2,
    float* __restrict__ mnf, float* __restrict__ scf,
    unsigned* __restrict__ pmn_g, unsigned* __restrict__ pmx_g,
    float4* __restrict__ gmeas, int B, int ipb) {
  cg::grid_group grid = cg::this_grid();
  const int tid = threadIdx.x;
  const int blk = blockIdx.x;
  const int lane = tid & 63;
  const int wave = tid >> 6;

  __shared__ float pmn[392], pmx[392];  // [row 0..27][col-pair 0..13]
  __shared__ float sU[256];
  __shared__ float smn[NP], ssc[NP];
  __shared__ unsigned rmn[4], rmx[4];

  // ---- P0a: block 0 computes U (16x16 circuit matrix) ----
  if (blk == 0 && tid < 16) {
    float cp[12], sp[12];
#pragma unroll
    for (int l = 0; l < 12; ++l) __sincosf(0.5f * params[l], &sp[l], &cp[l]);
    float st[16];
#pragma unroll
    for (int i = 0; i < 16; ++i) st[i] = 0.f;
    st[tid] = 1.f;  // basis vector -> column tid of U
#pragma unroll
    for (int l = 0; l < 3; ++l) {
#pragma unroll
      for (int q = 0; q < 4; ++q) {
        const float cq = cp[l * 4 + q], sq = sp[l * 4 + q];
        const int m = 8 >> q;
#pragma unroll
        for (int idx = 0; idx < 16; ++idx) {
          if (idx & m) continue;
          float v0 = st[idx], v1 = st[idx | m];
          st[idx] = cq * v0 - sq * v1;
          st[idx | m] = sq * v0 + cq * v1;
        }
      }
#pragma unroll
      for (int q = 0; q < 3; ++q) {
        const int mc = 8 >> q, mt = 4 >> q;
#pragma unroll
        for (int idx = 0; idx < 16; ++idx) {
          if ((idx & mc) && !(idx & mt)) {
            float t0 = st[idx];
            st[idx] = st[idx | mt];
            st[idx | mt] = t0;
          }
        }
      }
    }
#pragma unroll
    for (int i = 0; i < 16; ++i) Ug[i * 16 + tid] = st[i];
  }

  // ---- P0b: W2[k,p] = sum_c res_w[c]*cls_w[k, c*196+p] ----
  for (int t = blk * 256 + tid; t < 10 * NP; t += GRID * 256) {
    int k = t / NP, p = t - k * NP;
    float s = 0.f;
#pragma unroll
    for (int c = 0; c < 4; ++c) s += res_w[c] * cls_w[k * 784 + c * NP + p];
    W2[t] = s;
  }

  // ---- P0c: per-block patch min/max partial (images [blk*ipb, +ipb)) ----
  if (tid < NP) {
    const int img0 = blk * ipb;
    const int nimg = min(ipb, B - img0);
    const float* base = x + (size_t)img0 * 784 + 4 * tid;
    float mn0 = 3.4e38f, mx0 = -3.4e38f, mn1 = 3.4e38f, mx1 = -3.4e38f;
    for (int m = 0; m < nimg; ++m) {
      float4 v = *(const float4*)(base + (size_t)m * 784);
      mn0 = fminf(mn0, fminf(v.x, v.y));
      mx0 = fmaxf(mx0, fmaxf(v.x, v.y));
      mn1 = fminf(mn1, fminf(v.z, v.w));
      mx1 = fmaxf(mx1, fmaxf(v.z, v.w));
    }
    const int r = (4 * tid) / 28;
    const int jj = ((4 * tid) - 28 * r) >> 1;  // even; covers jj, jj+1
    pmn[r * 14 + jj] = mn0;
    pmx[r * 14 + jj] = mx0;
    pmn[r * 14 + jj + 1] = mn1;
    pmx[r * 14 + jj + 1] = mx1;
  }
  __syncthreads();
  if (tid < NP) {
    const int i = tid / 14, j = tid - i * 14;
    const int f0 = (2 * i) * 14 + j, f1 = f0 + 14;
    pmn_g[blk * NP + tid] = fkey(fminf(pmn[f0], pmn[f1]));
    pmx_g[blk * NP + tid] = fkey(fmaxf(pmx[f0], pmx[f1]));
  }

  grid.sync();

  // ---- P1: block p (< 196) reduces the GRID partials for patch p ----
  if (blk < NP) {
    unsigned kmn = 0xFFFFFFFFu, kmx = 0u;
    for (int w = tid; w < GRID; w += 256) {
      kmn = min(kmn, pmn_g[w * NP + blk]);
      kmx = max(kmx, pmx_g[w * NP + blk]);
    }
#pragma unroll
    for (int off = 32; off > 0; off >>= 1) {
      kmn = min(kmn, (unsigned)__shfl_down(kmn, off, 64));
      kmx = max(kmx, (unsigned)__shfl_down(kmx, off, 64));
    }
    if (lane == 0) { rmn[wave] = kmn; rmx[wave] = kmx; }
    __syncthreads();
    if (tid == 0) {
      unsigned fmn = min(min(rmn[0], rmn[1]), min(rmn[2], rmn[3]));
      unsigned fmx = max(max(rmx[0], rmx[1]), max(rmx[2], rmx[3]));
      const float mnv = funkey(fmn), mxv = funkey(fmx);
      mnf[blk] = mnv;
      scf[blk] = (0.5f * PI_F) / (mxv - mnv + 1e-8f);  // half-angle scale
    }
  }

  grid.sync();

  // ---- P2: circuits; two samples per thread share each U-row LDS read ----
  sU[tid] = Ug[tid];
  if (tid < NP) { smn[tid] = mnf[tid]; ssc[tid] = scf[tid]; }
  __syncthreads();

  const int G = B * NP;
  const int nGB = (G + 255) / 256;  // 256-sample blocks
  for (int gb = blk; gb < nGB; gb += 2 * GRID) {
    const int g0 = gb * 256 + tid;
    const int gb1 = gb + GRID;
    const bool has1 = gb1 < nGB;
    const int g1 = (has1 ? gb1 : gb) * 256 + tid;

    float st0[16], st1[16];
    load_state(x, smn, ssc, g0, st0);
    load_state(x, smn, ssc, g1, st1);

    float z0a = 0.f, z1a = 0.f, z2a = 0.f, z3a = 0.f;
    float z0b = 0.f, z1b = 0.f, z2b = 0.f, z3b = 0.f;
#pragma unroll
    for (int i2 = 0; i2 < 16; ++i2) {
      const float4 u0 = *(const float4*)&sU[i2 * 16 + 0];
      const float4 u1 = *(const float4*)&sU[i2 * 16 + 4];
      const float4 u2 = *(const float4*)&sU[i2 * 16 + 8];
      const float4 u3 = *(const float4*)&sU[i2 * 16 + 12];
      // sample A: 4 partial dot-4s
      float fa = u0.x * st0[0];
      fa = fmaf(u0.y, st0[1], fa);
      fa = fmaf(u0.z, st0[2], fa);
      fa = fmaf(u0.w, st0[3], fa);
      float fb = u1.x * st0[4];
      fb = fmaf(u1.y, st0[5], fb);
      fb = fmaf(u1.z, st0[6], fb);
      fb = fmaf(u1.w, st0[7], fb);
      float fc = u2.x * st0[8];
      fc = fmaf(u2.y, st0[9], fc);
      fc = fmaf(u2.z, st0[10], fc);
      fc = fmaf(u2.w, st0[11], fc);
      float fd = u3.x * st0[12];
      fd = fmaf(u3.y, st0[13], fd);
      fd = fmaf(u3.z, st0[14], fd);
      fd = fmaf(u3.w, st0[15], fd);
      const float fA = (fa + fb) + (fc + fd);
      // sample B
      float ga = u0.x * st1[0];
      ga = fmaf(u0.y, st1[1], ga);
      ga = fmaf(u0.z, st1[2], ga);
      ga = fmaf(u0.w, st1[3], ga);
      float gb_ = u1.x * st1[4];
      gb_ = fmaf(u1.y, st1[5], gb_);
      gb_ = fmaf(u1.z, st1[6], gb_);
      gb_ = fmaf(u1.w, st1[7], gb_);
      float gc = u2.x * st1[8];
      gc = fmaf(u2.y, st1[9], gc);
      gc = fmaf(u2.z, st1[10], gc);
      gc = fmaf(u2.w, st1[11], gc);
      float gd = u3.x * st1[12];
      gd = fmaf(u3.y, st1[13], gd);
      gd = fmaf(u3.z, st1[14], gd);
      gd = fmaf(u3.w, st1[15], gd);
      const float fB = (ga + gb_) + (gc + gd);
      // |f|^2 == 1: accumulate only bit-clear rows; z = 2*acc - 1
      if (!(i2 & 8)) { z0a = fmaf(fA, fA, z0a); z0b = fmaf(fB, fB, z0b); }
      if (!(i2 & 4)) { z1a = fmaf(fA, fA, z1a); z1b = fmaf(fB, fB, z1b); }
      if (!(i2 & 2)) { z2a = fmaf(fA, fA, z2a); z2b = fmaf(fB, fB, z2b); }
      if (!(i2 & 1)) { z3a = fmaf(fA, fA, z3a); z3b = fmaf(fB, fB, z3b); }
    }
    gmeas[g0] = make_float4(fmaf(2.f, z0a, -1.f), fmaf(2.f, z1a, -1.f),
                            fmaf(2.f, z2a, -1.f), fmaf(2.f, z3a, -1.f));
    if (has1)
      gmeas[g1] = make_float4(fmaf(2.f, z0b, -1.f), fmaf(2.f, z1b, -1.f),
                              fmaf(2.f, z2b, -1.f), fmaf(2.f, z3b, -1.f));
  }

  grid.sync();

  // ---- P3: classifier + residual + log_softmax; one wave per image ----
  const float4* cls_w4 = (const float4*)cls_w;
  for (int img = blk * 4 + wave; img < B; img += GRID * 4) {
    const float4* mrow = gmeas + (size_t)img * NP;
    const float* xrow = x + (size_t)img * 784;
    float acc[10];
#pragma unroll
    for (int k = 0; k < 10; ++k) acc[k] = 0.f;
    for (int t4 = lane; t4 < NP; t4 += 64) {
      const float4 v = mrow[t4];
#pragma unroll
      for (int k = 0; k < 10; ++k) {
        const float4 w = cls_w4[k * NP + t4];
        acc[k] = fmaf(v.x, w.x, fmaf(v.y, w.y, fmaf(v.z, w.z, fmaf(v.w, w.w, acc[k]))));
      }
    }
    for (int p = lane; p < NP; p += 64) {
      const int i = p / 14, j = p - i * 14;
      const float v = xrow[(2 * i) * 28 + 2 * j];
#pragma unroll
      for (int k = 0; k < 10; ++k) acc[k] = fmaf(v, W2[k * NP + p], acc[k]);
    }
#pragma unroll
    for (int k = 0; k < 10; ++k) {
      float a = acc[k];
#pragma unroll
      for (int off = 32; off > 0; off >>= 1) a += __shfl_down(a, off, 64);
      acc[k] = a;
    }
    if (lane == 0) {
      float lg[10];
#pragma unroll
      for (int k = 0; k < 10; ++k) lg[k] = acc[k] + cls_b[k];
      float m = lg[0];
#pragma unroll
      for (int k = 1; k < 10; ++k) m = fmaxf(m, lg[k]);
      float s = 0.f;
#pragma unroll
      for (int k = 0; k < 10; ++k) s += __expf(lg[k] - m);
      const float lse = m + __logf(s);
#pragma unroll
      for (int k = 0; k < 10; ++k) out[(size_t)img * 10 + k] = lg[k] - lse;
    }
  }
}

extern "C" void kernel_launch(void* const* d_in, const int* in_sizes, int n_in,
                              void* d_out, int out_size, void* d_ws, size_t ws_size,
                              hipStream_t stream) {
  const float* x      = (const float*)d_in[0];
  const float* params = (const float*)d_in[1];
  const float* res_w  = (const float*)d_in[2];
  const float* cls_w  = (const float*)d_in[3];
  const float* cls_b  = (const float*)d_in[4];
  float* out = (float*)d_out;
  int B = in_sizes[0] / 784;

  // ws layout (floats unless noted):
  // gmeas[B*784] | Ug[256] | W2[1960] | mnf[196] | scf[196] | pmn_g[GRID*196] u32 | pmx_g u32
  float4* gmeas = (float4*)d_ws;
  float* Ug  = (float*)d_ws + (size_t)B * 784;
  float* W2  = Ug + 256;
  float* mnf = W2 + 10 * NP;
  float* scf = mnf + NP;
  unsigned* pmn_g = (unsigned*)(scf + NP);
  unsigned* pmx_g = pmn_g + GRID * NP;

  int ipb = (B + GRID - 1) / GRID;  // images per block in P0

  void* args[] = {(void*)&x, (void*)&params, (void*)&res_w, (void*)&cls_w,
                  (void*)&cls_b, (void*)&out, (void*)&Ug, (void*)&W2,
                  (void*)&mnf, (void*)&scf, (void*)&pmn_g, (void*)&pmx_g,
                  (void*)&gmeas, (void*)&B, (void*)&ipb};
  hipLaunchCooperativeKernel((const void*)fused_kernel, dim3(GRID), dim3(256),
                             args, 0, stream);
}

// Round 8
// 143.348 us; speedup vs baseline: 3.3072x; 3.3072x over previous
//
#include <hip/hip_runtime.h>
#include <math.h>

#define NP 196
#define PI_F 3.14159265358979323846f

// order-preserving float<->uint encoding (monotone: min of keys == key of min)
__device__ __forceinline__ unsigned fkey(float f) {
  unsigned u = __float_as_uint(f);
  return u ^ ((unsigned)((int)u >> 31) | 0x80000000u);
}
__device__ __forceinline__ float funkey(unsigned k) {
  unsigned u = (k & 0x80000000u) ? (k ^ 0x80000000u) : ~k;
  return __uint_as_float(u);
}

// ---------------------------------------------------------------------------
// K1 (1 block): init min/max key slots + cos/sin of the 12 variational params.
// cs[2*l] = cos(params[l]/2), cs[2*l+1] = sin(params[l]/2), l = layer*4+q.
// ---------------------------------------------------------------------------
__global__ void __launch_bounds__(256) init_kernel(const float* __restrict__ params,
                                                   unsigned* __restrict__ mn,
                                                   unsigned* __restrict__ mx,
                                                   float* __restrict__ cs) {
  const int t = threadIdx.x;
  if (t < NP) { mn[t] = 0xFFFFFFFFu; mx[t] = 0u; }
  if (t < 12) {
    float c, s;
    __sincosf(0.5f * params[t], &s, &c);
    cs[2 * t] = c;
    cs[2 * t + 1] = s;
  }
}

// ---------------------------------------------------------------------------
// K2: per-patch min/max (proven R5 structure). Thread t<196 owns one float4
// slot of the image, register-reduces over `imgs` images, LDS row-combine,
// one global atomic per patch per block. 1024 blocks (8 images each).
// ---------------------------------------------------------------------------
__global__ void __launch_bounds__(256) minmax_kernel(
    const float* __restrict__ x, unsigned* __restrict__ mn,
    unsigned* __restrict__ mx, int imgs, int B) {
  __shared__ float pmn[392], pmx[392];  // [row 0..27][col-pair 0..13]
  const int t = threadIdx.x;
  const int img0 = blockIdx.x * imgs;
  if (t < NP) {
    const float* base = x + (size_t)img0 * 784 + 4 * t;
    float mn0 = 3.4e38f, mx0 = -3.4e38f, mn1 = 3.4e38f, mx1 = -3.4e38f;
    const int nimg = (img0 + imgs <= B) ? imgs : (B - img0);
#pragma unroll 4
    for (int m = 0; m < nimg; ++m) {
      float4 v = *(const float4*)(base + (size_t)m * 784);
      mn0 = fminf(mn0, fminf(v.x, v.y));
      mx0 = fmaxf(mx0, fmaxf(v.x, v.y));
      mn1 = fminf(mn1, fminf(v.z, v.w));
      mx1 = fmaxf(mx1, fmaxf(v.z, v.w));
    }
    const int r = (4 * t) / 28;
    const int jj = ((4 * t) - 28 * r) >> 1;  // even; covers jj, jj+1
    pmn[r * 14 + jj] = mn0;
    pmx[r * 14 + jj] = mx0;
    pmn[r * 14 + jj + 1] = mn1;
    pmx[r * 14 + jj + 1] = mx1;
  }
  __syncthreads();
  if (t < NP) {
    const int i = t / 14, j = t - i * 14;
    const int f0 = (2 * i) * 14 + j, f1 = f0 + 14;
    atomicMin(&mn[t], fkey(fminf(pmn[f0], pmn[f1])));
    atomicMax(&mx[t], fkey(fmaxf(pmx[f0], pmx[f1])));
  }
}

// ---------------------------------------------------------------------------
// K3: one block per image, fully fused: gate-by-gate circuit (c/s broadcast
// from LDS, no per-row ds_read_b128 stream), meas -> ovec[4p+w] in LDS,
// residual in-place (reuses r0.x), classifier dot + log_softmax.
// No gmeas round-trip; one dispatch replaces circuit+cls.
// ---------------------------------------------------------------------------
__global__ void __launch_bounds__(256, 6) fused_kernel(
    const float* __restrict__ x, const unsigned* __restrict__ mnk,
    const unsigned* __restrict__ mxk, const float* __restrict__ cs_g,
    const float* __restrict__ res_w, const float* __restrict__ cls_w,
    const float* __restrict__ cls_b, float* __restrict__ out) {
  __shared__ float scs[24];
  __shared__ float sres[4];
  __shared__ float ovec[784];
  __shared__ float wred[4][10];
  __shared__ float lg[10];
  const int tid = threadIdx.x;
  const int b = blockIdx.x;
  const int lane = tid & 63;
  const int wave = tid >> 6;

  if (tid < 24) scs[tid] = cs_g[tid];
  if (tid < 4) sres[tid] = res_w[tid];
  __syncthreads();

  const bool active = tid < NP;
  float r0x = 0.f;
  if (active) {
    const int p = tid;
    const int i = p / 14, j = p - i * 14;
    const float* px = x + (size_t)b * 784 + (2 * i) * 28 + 2 * j;
    const float2 r0 = *(const float2*)px;
    const float2 r1 = *(const float2*)(px + 28);
    r0x = r0.x;  // == x[b, 2i, 2j], reused for the residual below

    const float mnv = funkey(mnk[p]);
    const float mxv = funkey(mxk[p]);
    const float sc = (0.5f * PI_F) / (mxv - mnv + 1e-8f);  // half-angle scale

    float cc[4], ss[4];
    __sincosf((r0.x - mnv) * sc, &ss[0], &cc[0]);
    __sincosf((r0.y - mnv) * sc, &ss[1], &cc[1]);
    __sincosf((r1.x - mnv) * sc, &ss[2], &cc[2]);
    __sincosf((r1.y - mnv) * sc, &ss[3], &cc[3]);

    // product state; index bit (8>>q) = wire q
    float st[16];
    {
      const float A[4] = {cc[0] * cc[1], cc[0] * ss[1], ss[0] * cc[1], ss[0] * ss[1]};
      const float Bq[4] = {cc[2] * cc[3], cc[2] * ss[3], ss[2] * cc[3], ss[2] * ss[3]};
#pragma unroll
      for (int idx = 0; idx < 16; ++idx) st[idx] = A[idx >> 2] * Bq[idx & 3];
    }

    // 3 variational layers: RY each wire (c/s broadcast from LDS), CNOT chain
#pragma unroll
    for (int l = 0; l < 3; ++l) {
#pragma unroll
      for (int q = 0; q < 4; ++q) {
        const float cq = scs[2 * (l * 4 + q)];
        const float sq = scs[2 * (l * 4 + q) + 1];
        const int m = 8 >> q;
#pragma unroll
        for (int idx = 0; idx < 16; ++idx) {
          if (idx & m) continue;
          float v0 = st[idx], v1 = st[idx | m];
          st[idx] = cq * v0 - sq * v1;
          st[idx | m] = sq * v0 + cq * v1;
        }
      }
#pragma unroll
      for (int q = 0; q < 3; ++q) {  // CNOT(q,q+1): swap within control=1 half
        const int mc = 8 >> q, mt = 4 >> q;
#pragma unroll
        for (int idx = 0; idx < 16; ++idx) {
          if ((idx & mc) && !(idx & mt)) {
            float t0 = st[idx];
            st[idx] = st[idx | mt];
            st[idx | mt] = t0;
          }
        }
      }
    }

    // z_w = 2*sum_{bit_w clear} f^2 - 1  (|f|^2 == 1)
    float z0 = 0.f, z1 = 0.f, z2 = 0.f, z3 = 0.f;
#pragma unroll
    for (int idx = 0; idx < 16; ++idx) {
      const float f = st[idx];
      if (!(idx & 8)) z0 = fmaf(f, f, z0);
      if (!(idx & 4)) z1 = fmaf(f, f, z1);
      if (!(idx & 2)) z2 = fmaf(f, f, z2);
      if (!(idx & 1)) z3 = fmaf(f, f, z3);
    }
    ovec[4 * tid + 0] = fmaf(2.f, z0, -1.f);
    ovec[4 * tid + 1] = fmaf(2.f, z1, -1.f);
    ovec[4 * tid + 2] = fmaf(2.f, z2, -1.f);
    ovec[4 * tid + 3] = fmaf(2.f, z3, -1.f);
  }
  __syncthreads();

  // residual: ovec[c*196+p] += res_w[c] * x[b,2i,2j]  (r0x of thread p)
  if (active) {
#pragma unroll
    for (int c = 0; c < 4; ++c) ovec[c * NP + tid] += sres[c] * r0x;
  }
  __syncthreads();

  // classifier: logits[k] = cls_b[k] + dot(cls_w[k,:], ovec)
  float acc[10];
#pragma unroll
  for (int k = 0; k < 10; ++k) acc[k] = 0.f;
  for (int t = tid; t < 784; t += 256) {
    const float v = ovec[t];
#pragma unroll
    for (int k = 0; k < 10; ++k) acc[k] = fmaf(v, cls_w[k * 784 + t], acc[k]);
  }
#pragma unroll
  for (int k = 0; k < 10; ++k) {
    float a = acc[k];
#pragma unroll
    for (int off = 32; off > 0; off >>= 1) a += __shfl_down(a, off, 64);
    acc[k] = a;
  }
  if (lane == 0) {
#pragma unroll
    for (int k = 0; k < 10; ++k) wred[wave][k] = acc[k];
  }
  __syncthreads();
  if (tid < 10) {
    float s = cls_b[tid];
#pragma unroll
    for (int w = 0; w < 4; ++w) s += wred[w][tid];
    lg[tid] = s;
  }
  __syncthreads();
  if (tid < 10) {
    float m = lg[0];
#pragma unroll
    for (int k = 1; k < 10; ++k) m = fmaxf(m, lg[k]);
    float ssum = 0.f;
#pragma unroll
    for (int k = 0; k < 10; ++k) ssum += __expf(lg[k] - m);
    out[(size_t)b * 10 + tid] = lg[tid] - m - __logf(ssum);
  }
}

extern "C" void kernel_launch(void* const* d_in, const int* in_sizes, int n_in,
                              void* d_out, int out_size, void* d_ws, size_t ws_size,
                              hipStream_t stream) {
  const float* x      = (const float*)d_in[0];
  const float* params = (const float*)d_in[1];
  const float* res_w  = (const float*)d_in[2];
  const float* cls_w  = (const float*)d_in[3];
  const float* cls_b  = (const float*)d_in[4];
  float* out = (float*)d_out;
  const int B = in_sizes[0] / 784;

  // ws layout: mn[196] u32 | mx[196] u32 | cs[24] f32
  unsigned* mn = (unsigned*)d_ws;
  unsigned* mx = mn + NP;
  float* cs = (float*)(mx + NP);

  init_kernel<<<1, 256, 0, stream>>>(params, mn, mx, cs);

  const int imgs = 8;
  const int nblk = (B + imgs - 1) / imgs;
  minmax_kernel<<<nblk, 256, 0, stream>>>(x, mn, mx, imgs, B);

  fused_kernel<<<B, 256, 0, stream>>>(x, mn, mx, cs, res_w, cls_w, cls_b, out);
}